// Round 1
// baseline (252.156 us; speedup 1.0000x reference)
//
#include <hip/hip_runtime.h>
#include <math.h>

#define DEV __device__ __forceinline__

// One fully-unrolled linear layer: out[o] = b[o] + sum_k in[k]*w[o*DIN+k]
// Weight/bias indices are wave-uniform compile-time offsets -> compiler
// should scalarize these loads (s_load) and use SGPR operands in v_fma.
template <int DIN, int DOUT>
DEV void lin(const float* __restrict__ w, const float* __restrict__ b,
             const float* in, float* out) {
#pragma unroll
    for (int o = 0; o < DOUT; ++o) {
        float acc = b[o];
#pragma unroll
        for (int k = 0; k < DIN; ++k) {
            acc = fmaf(in[k], w[o * DIN + k], acc);
        }
        out[o] = acc;
    }
}

template <int N>
DEV void relu_ip(float* v) {
#pragma unroll
    for (int k = 0; k < N; ++k) v[k] = fmaxf(v[k], 0.0f);
}

template <int N>
DEV void add_relu_ip(float* v, const float* s) {
#pragma unroll
    for (int k = 0; k < N; ++k) v[k] = fmaxf(v[k] + s[k], 0.0f);
}

__global__ void __launch_bounds__(256)
csnet14_kernel(const float* __restrict__ x,
               const float* __restrict__ w1,  const float* __restrict__ b1,
               const float* __restrict__ w2,  const float* __restrict__ b2,
               const float* __restrict__ w3,  const float* __restrict__ b3,
               const float* __restrict__ w4,  const float* __restrict__ b4,
               const float* __restrict__ w5,  const float* __restrict__ b5,
               const float* __restrict__ w6,  const float* __restrict__ b6,
               const float* __restrict__ w7,  const float* __restrict__ b7,
               const float* __restrict__ w8,  const float* __restrict__ b8,
               const float* __restrict__ w9,  const float* __restrict__ b9,
               const float* __restrict__ w10, const float* __restrict__ b10,
               const float* __restrict__ w11, const float* __restrict__ b11,
               const float* __restrict__ w12, const float* __restrict__ b12,
               const float* __restrict__ w13, const float* __restrict__ b13,
               const float* __restrict__ w14, const float* __restrict__ b14,
               float* __restrict__ out, int n) {
    int i = blockIdx.x * blockDim.x + threadIdx.x;
    if (i >= n) return;

    // Load one 12-float row (48 B, 16B-aligned since 48 % 16 == 0).
    const float4* xr = reinterpret_cast<const float4*>(x + (size_t)i * 12);
    float4 v0 = xr[0];
    float4 v1 = xr[1];
    float4 v2 = xr[2];
    float h0[12] = {v0.x, v0.y, v0.z, v0.w,
                    v1.x, v1.y, v1.z, v1.w,
                    v2.x, v2.y, v2.z, v2.w};

    // Encoder: fc1..fc6, save post-ReLU identities.
    float id1[12]; lin<12, 12>(w1, b1, h0,  id1); relu_ip<12>(id1);
    float id2[11]; lin<12, 11>(w2, b2, id1, id2); relu_ip<11>(id2);
    float id3[10]; lin<11, 10>(w3, b3, id2, id3); relu_ip<10>(id3);
    float id4[9];  lin<10,  9>(w4, b4, id3, id4); relu_ip<9>(id4);
    float id5[8];  lin< 9,  8>(w5, b5, id4, id5); relu_ip<8>(id5);
    float id6[7];  lin< 8,  7>(w6, b6, id5, id6); relu_ip<7>(id6);

    // Bottleneck fc7.
    float t7[6];   lin< 7,  6>(w7, b7, id6, t7);  relu_ip<6>(t7);

    // Decoder: fc8..fc13 each adds matching identity before ReLU.
    float t8[7];   lin< 6,  7>(w8,  b8,  t7,  t8);  add_relu_ip<7>(t8,  id6);
    float t9[8];   lin< 7,  8>(w9,  b9,  t8,  t9);  add_relu_ip<8>(t9,  id5);
    float t10[9];  lin< 8,  9>(w10, b10, t9,  t10); add_relu_ip<9>(t10, id4);
    float t11[10]; lin< 9, 10>(w11, b11, t10, t11); add_relu_ip<10>(t11, id3);
    float t12[11]; lin<10, 11>(w12, b12, t11, t12); add_relu_ip<11>(t12, id2);
    float t13[12]; lin<11, 12>(w13, b13, t12, t13); add_relu_ip<12>(t13, id1);

    // fc14 (12 -> 2) + softmax over the 2 classes.
    float l[2];    lin<12,  2>(w14, b14, t13, l);
    float m  = fmaxf(l[0], l[1]);
    float e0 = __expf(l[0] - m);
    float e1 = __expf(l[1] - m);
    float inv = __builtin_amdgcn_rcpf(e0 + e1);

    float2 o;
    o.x = e0 * inv;
    o.y = e1 * inv;
    reinterpret_cast<float2*>(out)[i] = o;
}

extern "C" void kernel_launch(void* const* d_in, const int* in_sizes, int n_in,
                              void* d_out, int out_size, void* d_ws, size_t ws_size,
                              hipStream_t stream) {
    const float* x   = (const float*)d_in[0];
    const float* w1  = (const float*)d_in[1];  const float* b1  = (const float*)d_in[2];
    const float* w2  = (const float*)d_in[3];  const float* b2  = (const float*)d_in[4];
    const float* w3  = (const float*)d_in[5];  const float* b3  = (const float*)d_in[6];
    const float* w4  = (const float*)d_in[7];  const float* b4  = (const float*)d_in[8];
    const float* w5  = (const float*)d_in[9];  const float* b5  = (const float*)d_in[10];
    const float* w6  = (const float*)d_in[11]; const float* b6  = (const float*)d_in[12];
    const float* w7  = (const float*)d_in[13]; const float* b7  = (const float*)d_in[14];
    const float* w8  = (const float*)d_in[15]; const float* b8  = (const float*)d_in[16];
    const float* w9  = (const float*)d_in[17]; const float* b9  = (const float*)d_in[18];
    const float* w10 = (const float*)d_in[19]; const float* b10 = (const float*)d_in[20];
    const float* w11 = (const float*)d_in[21]; const float* b11 = (const float*)d_in[22];
    const float* w12 = (const float*)d_in[23]; const float* b12 = (const float*)d_in[24];
    const float* w13 = (const float*)d_in[25]; const float* b13 = (const float*)d_in[26];
    const float* w14 = (const float*)d_in[27]; const float* b14 = (const float*)d_in[28];
    float* out = (float*)d_out;

    const int n = in_sizes[0] / 12;  // 2,000,000 rows
    dim3 block(256);
    dim3 grid((n + 255) / 256);
    csnet14_kernel<<<grid, block, 0, stream>>>(
        x, w1, b1, w2, b2, w3, b3, w4, b4, w5, b5, w6, b6, w7, b7,
        w8, b8, w9, b9, w10, b10, w11, b11, w12, b12, w13, b13, w14, b14,
        out, n);
}

// Round 2
// 249.482 us; speedup vs baseline: 1.0107x; 1.0107x over previous
//
#include <hip/hip_runtime.h>
#include <math.h>

#define DEV __device__ __forceinline__

// One fully-unrolled linear layer: out[o] = b[o] + sum_k in[k]*w[o*DIN+k]
// Weight/bias indices are wave-uniform compile-time offsets -> scalarized
// s_load; v_fma with one SGPR operand (legal: max 1 SGPR per VALU inst).
template <int DIN, int DOUT>
DEV void lin(const float* __restrict__ w, const float* __restrict__ b,
             const float* in, float* out) {
#pragma unroll
    for (int o = 0; o < DOUT; ++o) {
        float acc = b[o];
#pragma unroll
        for (int k = 0; k < DIN; ++k) {
            acc = fmaf(in[k], w[o * DIN + k], acc);
        }
        out[o] = acc;
    }
}

template <int N>
DEV void relu_ip(float* v) {
#pragma unroll
    for (int k = 0; k < N; ++k) v[k] = fmaxf(v[k], 0.0f);
}

template <int N>
DEV void add_relu_ip(float* v, const float* s) {
#pragma unroll
    for (int k = 0; k < N; ++k) v[k] = fmaxf(v[k] + s[k], 0.0f);
}

// __launch_bounds__(256, 2): 2 waves/EU min -> up to 256 VGPR/wave. R1 evidence:
// default heuristic capped us at 36 VGPRs and spilled ~57 live floats to AGPRs
// (v_accvgpr VALU churn, ~2x instruction count, VGPR_Count=36 w/ zero scratch
// memory traffic). ~95 floats must live across the bottleneck.
__global__ void __launch_bounds__(256, 2)
csnet14_kernel(const float* __restrict__ x,
               const float* __restrict__ w1,  const float* __restrict__ b1,
               const float* __restrict__ w2,  const float* __restrict__ b2,
               const float* __restrict__ w3,  const float* __restrict__ b3,
               const float* __restrict__ w4,  const float* __restrict__ b4,
               const float* __restrict__ w5,  const float* __restrict__ b5,
               const float* __restrict__ w6,  const float* __restrict__ b6,
               const float* __restrict__ w7,  const float* __restrict__ b7,
               const float* __restrict__ w8,  const float* __restrict__ b8,
               const float* __restrict__ w9,  const float* __restrict__ b9,
               const float* __restrict__ w10, const float* __restrict__ b10,
               const float* __restrict__ w11, const float* __restrict__ b11,
               const float* __restrict__ w12, const float* __restrict__ b12,
               const float* __restrict__ w13, const float* __restrict__ b13,
               const float* __restrict__ w14, const float* __restrict__ b14,
               float* __restrict__ out, int n) {
    int i = blockIdx.x * blockDim.x + threadIdx.x;
    if (i >= n) return;

    // Load one 12-float row (48 B, 16B-aligned since 48 % 16 == 0).
    const float4* xr = reinterpret_cast<const float4*>(x + (size_t)i * 12);
    float4 v0 = xr[0];
    float4 v1 = xr[1];
    float4 v2 = xr[2];
    float h0[12] = {v0.x, v0.y, v0.z, v0.w,
                    v1.x, v1.y, v1.z, v1.w,
                    v2.x, v2.y, v2.z, v2.w};

    // Encoder: fc1..fc6, save post-ReLU identities.
    float id1[12]; lin<12, 12>(w1, b1, h0,  id1); relu_ip<12>(id1);
    float id2[11]; lin<12, 11>(w2, b2, id1, id2); relu_ip<11>(id2);
    float id3[10]; lin<11, 10>(w3, b3, id2, id3); relu_ip<10>(id3);
    float id4[9];  lin<10,  9>(w4, b4, id3, id4); relu_ip<9>(id4);
    float id5[8];  lin< 9,  8>(w5, b5, id4, id5); relu_ip<8>(id5);
    float id6[7];  lin< 8,  7>(w6, b6, id5, id6); relu_ip<7>(id6);

    // Bottleneck fc7.
    float t7[6];   lin< 7,  6>(w7, b7, id6, t7);  relu_ip<6>(t7);

    // Decoder: fc8..fc13 each adds matching identity before ReLU.
    float t8[7];   lin< 6,  7>(w8,  b8,  t7,  t8);  add_relu_ip<7>(t8,  id6);
    float t9[8];   lin< 7,  8>(w9,  b9,  t8,  t9);  add_relu_ip<8>(t9,  id5);
    float t10[9];  lin< 8,  9>(w10, b10, t9,  t10); add_relu_ip<9>(t10, id4);
    float t11[10]; lin< 9, 10>(w11, b11, t10, t11); add_relu_ip<10>(t11, id3);
    float t12[11]; lin<10, 11>(w12, b12, t11, t12); add_relu_ip<11>(t12, id2);
    float t13[12]; lin<11, 12>(w13, b13, t12, t13); add_relu_ip<12>(t13, id1);

    // fc14 (12 -> 2) + softmax over the 2 classes.
    float l[2];    lin<12,  2>(w14, b14, t13, l);
    float m  = fmaxf(l[0], l[1]);
    float e0 = __expf(l[0] - m);
    float e1 = __expf(l[1] - m);
    float inv = __builtin_amdgcn_rcpf(e0 + e1);

    float2 o;
    o.x = e0 * inv;
    o.y = e1 * inv;
    reinterpret_cast<float2*>(out)[i] = o;
}

extern "C" void kernel_launch(void* const* d_in, const int* in_sizes, int n_in,
                              void* d_out, int out_size, void* d_ws, size_t ws_size,
                              hipStream_t stream) {
    const float* x   = (const float*)d_in[0];
    const float* w1  = (const float*)d_in[1];  const float* b1  = (const float*)d_in[2];
    const float* w2  = (const float*)d_in[3];  const float* b2  = (const float*)d_in[4];
    const float* w3  = (const float*)d_in[5];  const float* b3  = (const float*)d_in[6];
    const float* w4  = (const float*)d_in[7];  const float* b4  = (const float*)d_in[8];
    const float* w5  = (const float*)d_in[9];  const float* b5  = (const float*)d_in[10];
    const float* w6  = (const float*)d_in[11]; const float* b6  = (const float*)d_in[12];
    const float* w7  = (const float*)d_in[13]; const float* b7  = (const float*)d_in[14];
    const float* w8  = (const float*)d_in[15]; const float* b8  = (const float*)d_in[16];
    const float* w9  = (const float*)d_in[17]; const float* b9  = (const float*)d_in[18];
    const float* w10 = (const float*)d_in[19]; const float* b10 = (const float*)d_in[20];
    const float* w11 = (const float*)d_in[21]; const float* b11 = (const float*)d_in[22];
    const float* w12 = (const float*)d_in[23]; const float* b12 = (const float*)d_in[24];
    const float* w13 = (const float*)d_in[25]; const float* b13 = (const float*)d_in[26];
    const float* w14 = (const float*)d_in[27]; const float* b14 = (const float*)d_in[28];
    float* out = (float*)d_out;

    const int n = in_sizes[0] / 12;  // 2,000,000 rows
    dim3 block(256);
    dim3 grid((n + 255) / 256);
    csnet14_kernel<<<grid, block, 0, stream>>>(
        x, w1, b1, w2, b2, w3, b3, w4, b4, w5, b5, w6, b6, w7, b7,
        w8, b8, w9, b9, w10, b10, w11, b11, w12, b12, w13, b13, w14, b14,
        out, n);
}

// Round 3
// 231.495 us; speedup vs baseline: 1.0892x; 1.0777x over previous
//
#include <hip/hip_runtime.h>
#include <math.h>

#define DEV __device__ __forceinline__

// Packed fp32 pair: lane .x = row A, lane .y = row B. v_pk_fma_f32 does both
// rows' MAC in one VALU inst (gfx950 packed fp32 = the 157 TF path), and all
// per-weight overhead (s_load / SGPR->VGPR movement) amortizes over 2 rows.
typedef float f2 __attribute__((ext_vector_type(2)));

DEV f2 splat(float s) { f2 r; r.x = s; r.y = s; return r; }

// out[o] = b[o] + sum_k in[k]*w[o*DIN+k], for a pair of rows at once.
template <int DIN, int DOUT>
DEV void lin2(const float* __restrict__ w, const float* __restrict__ b,
              const f2* in, f2* out) {
#pragma unroll
    for (int o = 0; o < DOUT; ++o) {
        f2 acc = splat(b[o]);
#pragma unroll
        for (int k = 0; k < DIN; ++k) {
            acc = __builtin_elementwise_fma(in[k], splat(w[o * DIN + k]), acc);
        }
        out[o] = acc;
    }
}

template <int N>
DEV void relu_ip(f2* v) {
#pragma unroll
    for (int k = 0; k < N; ++k) v[k] = __builtin_elementwise_max(v[k], splat(0.0f));
}

template <int N>
DEV void add_relu_ip(f2* v, const f2* s) {
#pragma unroll
    for (int k = 0; k < N; ++k)
        v[k] = __builtin_elementwise_max(v[k] + s[k], splat(0.0f));
}

// (256,2): allow up to 256 arch VGPRs/wave; packed working set ~160 regs.
__global__ void __launch_bounds__(256, 2)
csnet14_kernel(const float* __restrict__ x,
               const float* __restrict__ w1,  const float* __restrict__ b1,
               const float* __restrict__ w2,  const float* __restrict__ b2,
               const float* __restrict__ w3,  const float* __restrict__ b3,
               const float* __restrict__ w4,  const float* __restrict__ b4,
               const float* __restrict__ w5,  const float* __restrict__ b5,
               const float* __restrict__ w6,  const float* __restrict__ b6,
               const float* __restrict__ w7,  const float* __restrict__ b7,
               const float* __restrict__ w8,  const float* __restrict__ b8,
               const float* __restrict__ w9,  const float* __restrict__ b9,
               const float* __restrict__ w10, const float* __restrict__ b10,
               const float* __restrict__ w11, const float* __restrict__ b11,
               const float* __restrict__ w12, const float* __restrict__ b12,
               const float* __restrict__ w13, const float* __restrict__ b13,
               const float* __restrict__ w14, const float* __restrict__ b14,
               float* __restrict__ out, int nt) {
    int t = blockIdx.x * blockDim.x + threadIdx.x;
    if (t >= nt) return;  // nt = n/2 row-pairs, n even (2M)

    // Two adjacent rows: 24 contiguous floats = 6x float4 (96 B, 16B-aligned).
    const float4* xr = reinterpret_cast<const float4*>(x + (size_t)t * 24);
    float4 a0 = xr[0], a1 = xr[1], a2 = xr[2];
    float4 a3 = xr[3], a4 = xr[4], a5 = xr[5];
    float r0[12] = {a0.x, a0.y, a0.z, a0.w, a1.x, a1.y, a1.z, a1.w,
                    a2.x, a2.y, a2.z, a2.w};
    float r1[12] = {a3.x, a3.y, a3.z, a3.w, a4.x, a4.y, a4.z, a4.w,
                    a5.x, a5.y, a5.z, a5.w};
    f2 h0[12];
#pragma unroll
    for (int k = 0; k < 12; ++k) { h0[k].x = r0[k]; h0[k].y = r1[k]; }

    // Encoder: fc1..fc6, save post-ReLU identities.
    f2 id1[12]; lin2<12, 12>(w1, b1, h0,  id1); relu_ip<12>(id1);
    f2 id2[11]; lin2<12, 11>(w2, b2, id1, id2); relu_ip<11>(id2);
    f2 id3[10]; lin2<11, 10>(w3, b3, id2, id3); relu_ip<10>(id3);
    f2 id4[9];  lin2<10,  9>(w4, b4, id3, id4); relu_ip<9>(id4);
    f2 id5[8];  lin2< 9,  8>(w5, b5, id4, id5); relu_ip<8>(id5);
    f2 id6[7];  lin2< 8,  7>(w6, b6, id5, id6); relu_ip<7>(id6);

    // Bottleneck fc7.
    f2 t7[6];   lin2< 7,  6>(w7, b7, id6, t7);  relu_ip<6>(t7);

    // Decoder: fc8..fc13 each adds matching identity before ReLU.
    f2 t8[7];   lin2< 6,  7>(w8,  b8,  t7,  t8);  add_relu_ip<7>(t8,  id6);
    f2 t9[8];   lin2< 7,  8>(w9,  b9,  t8,  t9);  add_relu_ip<8>(t9,  id5);
    f2 t10[9];  lin2< 8,  9>(w10, b10, t9,  t10); add_relu_ip<9>(t10, id4);
    f2 t11[10]; lin2< 9, 10>(w11, b11, t10, t11); add_relu_ip<10>(t11, id3);
    f2 t12[11]; lin2<10, 11>(w12, b12, t11, t12); add_relu_ip<11>(t12, id2);
    f2 t13[12]; lin2<11, 12>(w13, b13, t12, t13); add_relu_ip<12>(t13, id1);

    // fc14 (12 -> 2) + softmax, both rows.
    f2 l[2];    lin2<12,  2>(w14, b14, t13, l);
    f2 m  = __builtin_elementwise_max(l[0], l[1]);
    f2 d0 = l[0] - m;
    f2 d1 = l[1] - m;
    float e0a = __expf(d0.x), e0b = __expf(d0.y);
    float e1a = __expf(d1.x), e1b = __expf(d1.y);
    float inva = __builtin_amdgcn_rcpf(e0a + e1a);
    float invb = __builtin_amdgcn_rcpf(e0b + e1b);

    float4 o;  // rows 2t, 2t+1 -> out[4t..4t+3], perfectly coalesced 16B/lane
    o.x = e0a * inva;
    o.y = e1a * inva;
    o.z = e0b * invb;
    o.w = e1b * invb;
    reinterpret_cast<float4*>(out)[t] = o;
}

extern "C" void kernel_launch(void* const* d_in, const int* in_sizes, int n_in,
                              void* d_out, int out_size, void* d_ws, size_t ws_size,
                              hipStream_t stream) {
    const float* x   = (const float*)d_in[0];
    const float* w1  = (const float*)d_in[1];  const float* b1  = (const float*)d_in[2];
    const float* w2  = (const float*)d_in[3];  const float* b2  = (const float*)d_in[4];
    const float* w3  = (const float*)d_in[5];  const float* b3  = (const float*)d_in[6];
    const float* w4  = (const float*)d_in[7];  const float* b4  = (const float*)d_in[8];
    const float* w5  = (const float*)d_in[9];  const float* b5  = (const float*)d_in[10];
    const float* w6  = (const float*)d_in[11]; const float* b6  = (const float*)d_in[12];
    const float* w7  = (const float*)d_in[13]; const float* b7  = (const float*)d_in[14];
    const float* w8  = (const float*)d_in[15]; const float* b8  = (const float*)d_in[16];
    const float* w9  = (const float*)d_in[17]; const float* b9  = (const float*)d_in[18];
    const float* w10 = (const float*)d_in[19]; const float* b10 = (const float*)d_in[20];
    const float* w11 = (const float*)d_in[21]; const float* b11 = (const float*)d_in[22];
    const float* w12 = (const float*)d_in[23]; const float* b12 = (const float*)d_in[24];
    const float* w13 = (const float*)d_in[25]; const float* b13 = (const float*)d_in[26];
    const float* w14 = (const float*)d_in[27]; const float* b14 = (const float*)d_in[28];
    float* out = (float*)d_out;

    const int n  = in_sizes[0] / 12;  // 2,000,000 rows (even)
    const int nt = n / 2;             // row-pairs
    dim3 block(256);
    dim3 grid((nt + 255) / 256);
    csnet14_kernel<<<grid, block, 0, stream>>>(
        x, w1, b1, w2, b2, w3, b3, w4, b4, w5, b5, w6, b6, w7, b7,
        w8, b8, w9, b9, w10, b10, w11, b11, w12, b12, w13, b13, w14, b14,
        out, nt);
}

// Round 4
// 230.047 us; speedup vs baseline: 1.0961x; 1.0063x over previous
//
#include <hip/hip_runtime.h>
#include <math.h>

#define DEV __device__ __forceinline__

// Packed fp32 pair: .x = row A, .y = row B -> v_pk_fma_f32 (2 rows/inst).
typedef float f2 __attribute__((ext_vector_type(2)));

DEV f2 splat(float s) { f2 r; r.x = s; r.y = s; return r; }

// k-OUTER linear layer. R3 evidence: o-outer re-read in[k] DOUT times/layer
// (~1172 reads/pair); with identities parked in AGPRs each re-read was a
// v_accvgpr shuttle -> ~3160 VALU insts/pair vs ~1500 useful. k-outer reads
// in[k] once per k; the hot regs become the DOUT accumulators (always written
// -> guaranteed arch-VGPR residency), and consecutive pk_fmas walk DOUT
// independent chains (dep distance >= 6 >= FMA latency).
template <int DIN, int DOUT>
DEV void lin2(const float* __restrict__ w, const float* __restrict__ b,
              const f2* in, f2* out) {
#pragma unroll
    for (int o = 0; o < DOUT; ++o) out[o] = splat(b[o]);
#pragma unroll
    for (int k = 0; k < DIN; ++k) {
        f2 xk = in[k];
#pragma unroll
        for (int o = 0; o < DOUT; ++o)
            out[o] = __builtin_elementwise_fma(xk, splat(w[o * DIN + k]), out[o]);
    }
}

// Same, but accumulator starts at bias + skip (fuses the decoder skip-add).
template <int DIN, int DOUT>
DEV void lin2_skip(const float* __restrict__ w, const float* __restrict__ b,
                   const f2* in, const f2* skip, f2* out) {
#pragma unroll
    for (int o = 0; o < DOUT; ++o) out[o] = splat(b[o]) + skip[o];
#pragma unroll
    for (int k = 0; k < DIN; ++k) {
        f2 xk = in[k];
#pragma unroll
        for (int o = 0; o < DOUT; ++o)
            out[o] = __builtin_elementwise_fma(xk, splat(w[o * DIN + k]), out[o]);
    }
}

template <int N>
DEV void relu_ip(f2* v) {
#pragma unroll
    for (int k = 0; k < N; ++k) v[k] = __builtin_elementwise_max(v[k], splat(0.0f));
}

__global__ void __launch_bounds__(256, 2)
csnet14_kernel(const float* __restrict__ x,
               const float* __restrict__ w1,  const float* __restrict__ b1,
               const float* __restrict__ w2,  const float* __restrict__ b2,
               const float* __restrict__ w3,  const float* __restrict__ b3,
               const float* __restrict__ w4,  const float* __restrict__ b4,
               const float* __restrict__ w5,  const float* __restrict__ b5,
               const float* __restrict__ w6,  const float* __restrict__ b6,
               const float* __restrict__ w7,  const float* __restrict__ b7,
               const float* __restrict__ w8,  const float* __restrict__ b8,
               const float* __restrict__ w9,  const float* __restrict__ b9,
               const float* __restrict__ w10, const float* __restrict__ b10,
               const float* __restrict__ w11, const float* __restrict__ b11,
               const float* __restrict__ w12, const float* __restrict__ b12,
               const float* __restrict__ w13, const float* __restrict__ b13,
               const float* __restrict__ w14, const float* __restrict__ b14,
               float* __restrict__ out, int nt) {
    int t = blockIdx.x * blockDim.x + threadIdx.x;
    if (t >= nt) return;  // nt = n/2 row-pairs

    // Two adjacent rows: 24 contiguous floats = 6x float4 (96 B).
    const float4* xr = reinterpret_cast<const float4*>(x + (size_t)t * 24);
    float4 a0 = xr[0], a1 = xr[1], a2 = xr[2];
    float4 a3 = xr[3], a4 = xr[4], a5 = xr[5];
    float r0[12] = {a0.x, a0.y, a0.z, a0.w, a1.x, a1.y, a1.z, a1.w,
                    a2.x, a2.y, a2.z, a2.w};
    float r1[12] = {a3.x, a3.y, a3.z, a3.w, a4.x, a4.y, a4.z, a4.w,
                    a5.x, a5.y, a5.z, a5.w};
    f2 h0[12];
#pragma unroll
    for (int k = 0; k < 12; ++k) { h0[k].x = r0[k]; h0[k].y = r1[k]; }

    // Encoder: fc1..fc6, save post-ReLU identities.
    f2 id1[12]; lin2<12, 12>(w1, b1, h0,  id1); relu_ip<12>(id1);
    f2 id2[11]; lin2<12, 11>(w2, b2, id1, id2); relu_ip<11>(id2);
    f2 id3[10]; lin2<11, 10>(w3, b3, id2, id3); relu_ip<10>(id3);
    f2 id4[9];  lin2<10,  9>(w4, b4, id3, id4); relu_ip<9>(id4);
    f2 id5[8];  lin2< 9,  8>(w5, b5, id4, id5); relu_ip<8>(id5);
    f2 id6[7];  lin2< 8,  7>(w6, b6, id5, id6); relu_ip<7>(id6);

    // Bottleneck fc7.
    f2 t7[6];   lin2< 7,  6>(w7, b7, id6, t7);  relu_ip<6>(t7);

    // Decoder: fc8..fc13, skip fused into accumulator init.
    f2 t8[7];   lin2_skip< 6,  7>(w8,  b8,  t7,  id6, t8);  relu_ip<7>(t8);
    f2 t9[8];   lin2_skip< 7,  8>(w9,  b9,  t8,  id5, t9);  relu_ip<8>(t9);
    f2 t10[9];  lin2_skip< 8,  9>(w10, b10, t9,  id4, t10); relu_ip<9>(t10);
    f2 t11[10]; lin2_skip< 9, 10>(w11, b11, t10, id3, t11); relu_ip<10>(t11);
    f2 t12[11]; lin2_skip<10, 11>(w12, b12, t11, id2, t12); relu_ip<11>(t12);
    f2 t13[12]; lin2_skip<11, 12>(w13, b13, t12, id1, t13); relu_ip<12>(t13);

    // fc14 (12 -> 2) + softmax, both rows.
    f2 l[2];    lin2<12,  2>(w14, b14, t13, l);
    f2 m  = __builtin_elementwise_max(l[0], l[1]);
    f2 d0 = l[0] - m;
    f2 d1 = l[1] - m;
    float e0a = __expf(d0.x), e0b = __expf(d0.y);
    float e1a = __expf(d1.x), e1b = __expf(d1.y);
    float inva = __builtin_amdgcn_rcpf(e0a + e1a);
    float invb = __builtin_amdgcn_rcpf(e0b + e1b);

    float4 o;  // rows 2t, 2t+1 -> out[4t..4t+3], coalesced 16 B/lane
    o.x = e0a * inva;
    o.y = e1a * inva;
    o.z = e0b * invb;
    o.w = e1b * invb;
    reinterpret_cast<float4*>(out)[t] = o;
}

extern "C" void kernel_launch(void* const* d_in, const int* in_sizes, int n_in,
                              void* d_out, int out_size, void* d_ws, size_t ws_size,
                              hipStream_t stream) {
    const float* x   = (const float*)d_in[0];
    const float* w1  = (const float*)d_in[1];  const float* b1  = (const float*)d_in[2];
    const float* w2  = (const float*)d_in[3];  const float* b2  = (const float*)d_in[4];
    const float* w3  = (const float*)d_in[5];  const float* b3  = (const float*)d_in[6];
    const float* w4  = (const float*)d_in[7];  const float* b4  = (const float*)d_in[8];
    const float* w5  = (const float*)d_in[9];  const float* b5  = (const float*)d_in[10];
    const float* w6  = (const float*)d_in[11]; const float* b6  = (const float*)d_in[12];
    const float* w7  = (const float*)d_in[13]; const float* b7  = (const float*)d_in[14];
    const float* w8  = (const float*)d_in[15]; const float* b8  = (const float*)d_in[16];
    const float* w9  = (const float*)d_in[17]; const float* b9  = (const float*)d_in[18];
    const float* w10 = (const float*)d_in[19]; const float* b10 = (const float*)d_in[20];
    const float* w11 = (const float*)d_in[21]; const float* b11 = (const float*)d_in[22];
    const float* w12 = (const float*)d_in[23]; const float* b12 = (const float*)d_in[24];
    const float* w13 = (const float*)d_in[25]; const float* b13 = (const float*)d_in[26];
    const float* w14 = (const float*)d_in[27]; const float* b14 = (const float*)d_in[28];
    float* out = (float*)d_out;

    const int n  = in_sizes[0] / 12;  // 2,000,000 rows (even)
    const int nt = n / 2;             // row-pairs
    dim3 block(256);
    dim3 grid((nt + 255) / 256);
    csnet14_kernel<<<grid, block, 0, stream>>>(
        x, w1, b1, w2, b2, w3, b3, w4, b4, w5, b5, w6, b6, w7, b7,
        w8, b8, w9, b9, w10, b10, w11, b11, w12, b12, w13, b13, w14, b14,
        out, nt);
}